// Round 4
// baseline (406.927 us; speedup 1.0000x reference)
//
#include <hip/hip_runtime.h>
#include <hip/hip_bf16.h>

// LSTM_single_task: B=32768, I=H=512. Live math: 3 gate GEMMs (i,c,o) over
// u=[x,h] (K=1024), fused activations. f-gate and c_prev are dead code.
//
// R6: vs R5 (380 us total; gemm 131 us @ 786 TF = 2-phase structure ceiling,
// 0 conflicts, FETCH 82 MB; prep ~50 us). R5 post-mortem: dbuf prefetch was
// NEUTRAL (cross-block overlap already hid staging latency, m99/m100 lesson);
// rcp epilogue cut VALUBusy 48->27 but was off critical path.
// This round: eliminate pack_u entirely (it streamed 192 MB just to
// pre-convert A; A-rows are block-local):
//  - fp32 path: reg-stage A per step (T14 issue-early/write-late): 8 f32x4
//    coalesced loads issued BEFORE compute, cvt+4 swizzled ds_write_b128
//    AFTER compute (buffer nxt last read at t-1, retired by t-1 barrier ->
//    race-free). Reader/LDS layout unchanged.
//  - bf16 path: A via global_load_lds directly from x/h (stride 512).
//  - prep = weights only (~9 MB, ~8 us). Net ~140 MB HBM + 1 dispatch saved.
//  - ws requirement drops to 3 MB (Wt only).

typedef unsigned short u16;
typedef u16 u16x8 __attribute__((ext_vector_type(8)));
typedef __bf16 bf16x8 __attribute__((ext_vector_type(8)));
typedef float f32x4 __attribute__((ext_vector_type(4)));

#define B_DIM 32768
#define H_DIM 512
#define K_DIM 1024
#define BH_ELEMS (B_DIM * H_DIM)          // 16,777,216
#define WT_BYTES ((size_t)(3u * 512u * 1024u * 2u)) // 3,145,728

#define GLOBAL_AS(p) ((__attribute__((address_space(1))) void*)(p))
#define LDS_AS(p)    ((__attribute__((address_space(3))) void*)(p))

__device__ __forceinline__ float bf2f(u16 u) {
    unsigned v = ((unsigned)u) << 16;
    float f;
    __builtin_memcpy(&f, &v, 4);
    return f;
}

__device__ __forceinline__ u16 f2bf16u(float f) {
    __hip_bfloat16 b = __float2bfloat16(f);   // RNE
    u16 u;
    __builtin_memcpy(&u, &b, 2);
    return u;
}

__device__ __forceinline__ float fast_rcp(float x) {
    return __builtin_amdgcn_rcpf(x);          // ~1 ulp approx; fine vs bf16 noise
}

__device__ __forceinline__ float fast_sigmoid(float x) {
    return fast_rcp(1.0f + __expf(-x));
}

__device__ __forceinline__ float fast_tanh(float x) {
    float e = __expf(-2.0f * fabsf(x));     // in (0,1], never overflows
    float r = (1.0f - e) * fast_rcp(1.0f + e);
    return x < 0.0f ? -r : r;
}

// Wave-uniform dtype classification from x's first 64 words. fp32 N(0,1):
// low u16 ~ uniform -> ~16% bf16-exponent-sane. bf16: low u16 IS bf16 -> ~100%.
__device__ __forceinline__ bool derive_isbf(const unsigned* __restrict__ x, int tid) {
    const unsigned lo = x[tid & 63] & 0xFFFFu;
    const unsigned e = (lo >> 7) & 0xFFu;
    const bool sane = (e >= 100u && e <= 140u) || (lo == 0u);
    return __popcll(__ballot(sane)) >= 48;
}

// direct global->LDS, 16 B per lane; LDS dest = wave-uniform base + lane*16
__device__ __forceinline__ void gload16(const u16* g, u16* l) {
    __builtin_amdgcn_global_load_lds(GLOBAL_AS((u16*)g), LDS_AS(l), 16, 0, 0);
}

// -------- prep: pack W into Wt[g][n][k] (bf16), n-major, k = [Wx ; Wh] -----
// grid 1536: bid -> (g,half,ktile,ntile); 32x32 LDS transpose, 256 thr.
__global__ __launch_bounds__(256) void prep(
    const void* __restrict__ x,
    const void* __restrict__ Wxi, const void* __restrict__ Whi,
    const void* __restrict__ Wxc, const void* __restrict__ Whc,
    const void* __restrict__ Wxo, const void* __restrict__ Who,
    u16* __restrict__ Wt)
{
    __shared__ u16 tile[32][33];
    const int tid = threadIdx.x;
    const bool isbf = derive_isbf((const unsigned*)x, tid);
    const int bid = blockIdx.x;

    const int bz = bid >> 8, rem = bid & 255;
    const int by = rem >> 4, bx = rem & 15;
    const int g = bz >> 1, half = bz & 1;
    const void* src;
    if (g == 0)      src = half ? Whi : Wxi;
    else if (g == 1) src = half ? Whc : Wxc;
    else             src = half ? Who : Wxo;
    const int kk = by * 32, nn = bx * 32;
    const int tx = tid & 31, ty = tid >> 5;
    if (isbf) {
        const u16* s = (const u16*)src;
#pragma unroll
        for (int i2 = 0; i2 < 4; ++i2)
            tile[ty + 8 * i2][tx] = s[(kk + ty + 8 * i2) * 512 + nn + tx];
    } else {
        const float* s = (const float*)src;
#pragma unroll
        for (int i2 = 0; i2 < 4; ++i2)
            tile[ty + 8 * i2][tx] = f2bf16u(s[(kk + ty + 8 * i2) * 512 + nn + tx]);
    }
    __syncthreads();
#pragma unroll
    for (int i2 = 0; i2 < 4; ++i2)
        Wt[(long)g * 524288 + (long)(nn + ty + 8 * i2) * 1024 + half * 512 + kk + tx]
            = tile[tx][ty + 8 * i2];
}

// -------- main v4: bf16 GEMM, BK=64, dbuf, A staged straight from x/h -----
// grid 2048 (flat): swz -> m-tile (128 rows) x n-tile (64 cols). 256 thr.
// LDS rows are 128 B (8 x 16B chunks); swizzle: stored chunk p holds global
// chunk k2 = p ^ (row&7). 2-way bank aliasing only (free).
__global__ __launch_bounds__(256, 2) void lstm_gemm_v4(
    const void* __restrict__ x, const void* __restrict__ h,
    const u16* __restrict__ Wt,
    const void* __restrict__ bxi, const void* __restrict__ bxc,
    const void* __restrict__ bxo, void* __restrict__ out)
{
    __shared__ __align__(16) u16 As[2][128 * 64];    // 2 x 16 KB
    __shared__ __align__(16) u16 Bs[2][3 * 64 * 64]; // 2 x 24 KB

    const int tid    = threadIdx.x;
    const bool isbf  = derive_isbf((const unsigned*)x, tid);
    const int lane   = tid & 63;
    const int wave   = tid >> 6;
    const int wave_m = wave & 1;
    const int wave_n = wave >> 1;

    // XCD-chunked swizzle: XCD x owns m-panels [32x, 32x+32); the 8 n-tiles
    // of a panel launch consecutively on that XCD -> x/h panel L2-resident.
    const int swz = (blockIdx.x & 7) * 256 + (blockIdx.x >> 3);
    const int m0 = (swz >> 3) * 128;
    const int n0 = (swz & 7) * 64;

    // ---- B staging sources (pre-swizzled per-lane, from Wt, stride 1024) --
    const int srow = lane >> 3;
    const int sk2  = (lane & 7) ^ srow;
    const u16* b_src[6];
#pragma unroll
    for (int q = 0; q < 6; ++q) {
        const int cb = q * 4 + wave;                 // 24 chunks = 3 gates x 64 n
        const int g = cb >> 3;
        const int nrow = (cb & 7) * 8 + srow;
        b_src[q] = Wt + (long)g * 524288 + (long)(n0 + nrow) * 1024 + sk2 * 8;
    }
    // ---- A staging (bf16 path): gload_lds straight from x/h, stride 512 ---
    // tile row for (wave,j): (wave*4+j)*8 + (lane>>3); fetches global chunk sk2.
    long a_goff[4];                                  // row*512 + sk2*8 (u16 idx)
#pragma unroll
    for (int j = 0; j < 4; ++j) {
        const int trow = (wave * 4 + j) * 8 + srow;
        a_goff[j] = (long)(m0 + trow) * 512 + sk2 * 8;
    }
    // ---- A staging (fp32 path): per-thread reg chunks ---------------------
    // chunk id = tid + 256*j -> row = (tid>>3)+32j, c8 = tid&7 (const).
    const int arow  = tid >> 3;          // 0..31
    const int ac8   = tid & 7;           // which 8-elem k-chunk
    const int aslot = (ac8 ^ (arow & 7)) * 8;        // swizzled slot (u16 idx)

#define STAGE_B(bi, kofs) do {                                            \
    _Pragma("unroll")                                                     \
    for (int q_ = 0; q_ < 6; ++q_)                                        \
        gload16(b_src[q_] + (kofs), &Bs[bi][(q_ * 4 + wave) * 512]);      \
} while (0)

#define STAGE_A_BF(bi, srcp, koff) do {                                   \
    _Pragma("unroll")                                                     \
    for (int j_ = 0; j_ < 4; ++j_)                                        \
        gload16((const u16*)(srcp) + a_goff[j_] + (koff),                 \
                &As[bi][(wave * 4 + j_) * 512]);                          \
} while (0)

#define A_LOAD_F32(srcp, koff) do {                                       \
    _Pragma("unroll")                                                     \
    for (int j_ = 0; j_ < 4; ++j_) {                                      \
        const float* p_ = (const float*)(srcp)                            \
            + (long)(m0 + arow + 32 * j_) * 512 + (koff) + ac8 * 8;       \
        alo[j_] = *(const f32x4*)p_;                                      \
        ahi[j_] = *(const f32x4*)(p_ + 4);                                \
    }                                                                     \
} while (0)

#define A_CVT_WRITE(bi) do {                                              \
    _Pragma("unroll")                                                     \
    for (int j_ = 0; j_ < 4; ++j_) {                                      \
        bf16x8 v_;                                                        \
        _Pragma("unroll")                                                 \
        for (int e_ = 0; e_ < 4; ++e_) {                                  \
            v_[e_]     = (__bf16)alo[j_][e_];                             \
            v_[4 + e_] = (__bf16)ahi[j_][e_];                             \
        }                                                                 \
        *(bf16x8*)&As[bi][(arow + 32 * j_) * 64 + aslot] = v_;            \
    }                                                                     \
} while (0)

    // ---- fragment ds_read offsets (u16 index), kk=0; kk=1 is idx^32 ------
    int a_off[4];
#pragma unroll
    for (int mt = 0; mt < 4; ++mt) {
        const int row = wave_m * 64 + mt * 16 + (lane & 15);
        const int p = (lane >> 4) ^ (row & 7);
        a_off[mt] = row * 64 + p * 8;
    }
    int b_off[3][2];
#pragma unroll
    for (int g = 0; g < 3; ++g)
#pragma unroll
        for (int nt = 0; nt < 2; ++nt) {
            const int row = wave_n * 32 + nt * 16 + (lane & 15);
            const int p = (lane >> 4) ^ (row & 7);
            b_off[g][nt] = g * 4096 + row * 64 + p * 8;
        }

    f32x4 acc[3][4][2];
    const f32x4 zero = {0.f, 0.f, 0.f, 0.f};
#pragma unroll
    for (int g = 0; g < 3; ++g)
#pragma unroll
        for (int mt = 0; mt < 4; ++mt)
#pragma unroll
            for (int nt = 0; nt < 2; ++nt)
                acc[g][mt][nt] = zero;

    f32x4 alo[4], ahi[4];                     // fp32 A in-flight regs (T14)

    // ---- prologue: stage tile 0 ------------------------------------------
    if (isbf) {
        STAGE_A_BF(0, x, 0);
    } else {
        A_LOAD_F32(x, 0);
    }
    STAGE_B(0, 0);
    if (!isbf) A_CVT_WRITE(0);
    __syncthreads();                          // tile 0 staged

    // ---- K loop: 16 steps of BK=64, double-buffered, 1 barrier/step ------
    // fp32 path: A global loads issue BEFORE compute (latency hidden under
    // ~1900cy of MFMA), cvt+ds_write AFTER compute (T14 write-late; buffer
    // nxt last read at t-1, retired by the t-1 barrier -> race-free).
#pragma unroll 2
    for (int t = 0; t < 16; ++t) {
        const int cur = t & 1;
        const int nxt = cur ^ 1;
        if (t < 15) {
            const int kb = (t + 1) * 64;
            const void* srcp = (kb < 512) ? x : h;
            const int koff = kb & 511;
            if (isbf) STAGE_A_BF(nxt, srcp, koff);
            else      A_LOAD_F32(srcp, koff);
            STAGE_B(nxt, kb);
        }

#pragma unroll
        for (int kk = 0; kk < 2; ++kk) {
            const int kx = kk * 32;           // chunk^4 <=> u16 idx ^ 32
            bf16x8 af[4];
#pragma unroll
            for (int mt = 0; mt < 4; ++mt)
                af[mt] = *(const bf16x8*)&As[cur][a_off[mt] ^ kx];
            bf16x8 bfr[3][2];
#pragma unroll
            for (int g = 0; g < 3; ++g)
#pragma unroll
                for (int nt = 0; nt < 2; ++nt)
                    bfr[g][nt] = *(const bf16x8*)&Bs[cur][b_off[g][nt] ^ kx];

#pragma unroll
            for (int g = 0; g < 3; ++g)
#pragma unroll
                for (int mt = 0; mt < 4; ++mt)
#pragma unroll
                    for (int nt = 0; nt < 2; ++nt)
                        acc[g][mt][nt] = __builtin_amdgcn_mfma_f32_16x16x32_bf16(
                            af[mt], bfr[g][nt], acc[g][mt][nt], 0, 0, 0);
        }
        if (t < 15) {
            if (!isbf) A_CVT_WRITE(nxt);
            __syncthreads();                  // stage landed + reads retired
        }
    }
#undef STAGE_B
#undef STAGE_A_BF
#undef A_LOAD_F32
#undef A_CVT_WRITE

    // ---- epilogue: bias + activations + store (dtype-matched) -------------
    // C/D layout: col = lane&15, row = (lane>>4)*4 + reg  [m89/m91 verified]
    const int colbase = n0 + wave_n * 32 + (lane & 15);
    float bi[2], bc[2], bo[2];
#pragma unroll
    for (int nt = 0; nt < 2; ++nt) {
        const int col = colbase + nt * 16;
        if (isbf) {
            bi[nt] = bf2f(((const u16*)bxi)[col]);
            bc[nt] = bf2f(((const u16*)bxc)[col]);
            bo[nt] = bf2f(((const u16*)bxo)[col]);
        } else {
            bi[nt] = ((const float*)bxi)[col];
            bc[nt] = ((const float*)bxc)[col];
            bo[nt] = ((const float*)bxo)[col];
        }
    }

    const int rowbase = m0 + wave_m * 64 + (lane >> 4) * 4;
#pragma unroll
    for (int mt = 0; mt < 4; ++mt)
#pragma unroll
        for (int nt = 0; nt < 2; ++nt)
#pragma unroll
            for (int r = 0; r < 4; ++r) {
                const int row = rowbase + mt * 16 + r;
                const int col = colbase + nt * 16;
                const float iv = fast_sigmoid(acc[0][mt][nt][r] + bi[nt]);
                const float cv = iv * fast_tanh(acc[1][mt][nt][r] + bc[nt]);
                const float ov = fast_sigmoid(acc[2][mt][nt][r] + bo[nt]);
                const float hv = ov * fast_tanh(cv);
                const long idx = (long)row * 512 + col;
                if (isbf) {
                    ((u16*)out)[idx]            = f2bf16u(hv);
                    ((u16*)out)[BH_ELEMS + idx] = f2bf16u(cv);
                } else {
                    ((float*)out)[idx]            = hv;
                    ((float*)out)[BH_ELEMS + idx] = cv;
                }
            }
}

// -------- fallback (R2-style): used only if ws can't even hold Wt ---------
__global__ __launch_bounds__(256, 2) void lstm_gemm_fb(
    const void* __restrict__ x, const void* __restrict__ h,
    const u16* __restrict__ Wt,
    const void* __restrict__ bxi, const void* __restrict__ bxc,
    const void* __restrict__ bxo, void* __restrict__ out)
{
    __shared__ __align__(16) u16 As[128 * 32];
    __shared__ __align__(16) u16 Bs[3 * 64 * 32];

    const int tid    = threadIdx.x;
    const bool isbf  = derive_isbf((const unsigned*)x, tid);
    const int lane   = tid & 63;
    const int wave   = tid >> 6;
    const int wave_m = wave & 1;
    const int wave_n = wave >> 1;
    const int m0 = blockIdx.y * 128;
    const int n0 = blockIdx.x * 64;

    const int trow = tid >> 2, tkc = (tid & 3) * 8;
    const long a_g0 = (long)(m0 + trow)      * 512 + tkc;
    const long a_g1 = (long)(m0 + 64 + trow) * 512 + tkc;
    const int  a_l0 = tid * 8;
    const int  a_l1 = 2048 + tid * 8;
    long b_g[3];
#pragma unroll
    for (int q = 0; q < 3; ++q)
        b_g[q] = (long)q * 524288 + (long)(n0 + trow) * 1024 + tkc;

    int a_ld[4];
#pragma unroll
    for (int mt = 0; mt < 4; ++mt)
        a_ld[mt] = (wave_m * 64 + mt * 16 + (lane & 15)) * 32 + (lane >> 4) * 8;
    int b_ld[3][2];
#pragma unroll
    for (int g = 0; g < 3; ++g)
#pragma unroll
        for (int nt = 0; nt < 2; ++nt)
            b_ld[g][nt] = g * 2048 + (wave_n * 32 + nt * 16 + (lane & 15)) * 32 + (lane >> 4) * 8;

    f32x4 acc[3][4][2];
    const f32x4 zero = {0.f, 0.f, 0.f, 0.f};
#pragma unroll
    for (int g = 0; g < 3; ++g)
#pragma unroll
        for (int mt = 0; mt < 4; ++mt)
#pragma unroll
            for (int nt = 0; nt < 2; ++nt)
                acc[g][mt][nt] = zero;

    for (int k0 = 0; k0 < K_DIM; k0 += 32) {
        const void* src = (k0 < 512) ? x : h;
        const long kadj = (k0 < 512) ? k0 : (k0 - 512);

        bf16x8 av0, av1, bv[3];
        if (isbf) {
            const u16* s = (const u16*)src + kadj;
            u16x8 t0 = *(const u16x8*)(s + a_g0);
            u16x8 t1 = *(const u16x8*)(s + a_g1);
            __builtin_memcpy(&av0, &t0, 16);
            __builtin_memcpy(&av1, &t1, 16);
        } else {
            const float* s = (const float*)src + kadj;
            f32x4 p0 = *(const f32x4*)(s + a_g0);
            f32x4 p1 = *(const f32x4*)(s + a_g0 + 4);
            f32x4 q0 = *(const f32x4*)(s + a_g1);
            f32x4 q1 = *(const f32x4*)(s + a_g1 + 4);
#pragma unroll
            for (int j = 0; j < 4; ++j) {
                av0[j] = (__bf16)p0[j]; av0[4 + j] = (__bf16)p1[j];
                av1[j] = (__bf16)q0[j]; av1[4 + j] = (__bf16)q1[j];
            }
        }
#pragma unroll
        for (int q = 0; q < 3; ++q) {
            u16x8 t = *(const u16x8*)(Wt + b_g[q] + k0);
            __builtin_memcpy(&bv[q], &t, 16);
        }

        __syncthreads();
        *(bf16x8*)&As[a_l0] = av0;
        *(bf16x8*)&As[a_l1] = av1;
#pragma unroll
        for (int q = 0; q < 3; ++q)
            *(bf16x8*)&Bs[q * 2048 + tid * 8] = bv[q];
        __syncthreads();

        bf16x8 af[4];
#pragma unroll
        for (int mt = 0; mt < 4; ++mt)
            af[mt] = *(const bf16x8*)&As[a_ld[mt]];
        bf16x8 bfr[3][2];
#pragma unroll
        for (int g = 0; g < 3; ++g)
#pragma unroll
            for (int nt = 0; nt < 2; ++nt)
                bfr[g][nt] = *(const bf16x8*)&Bs[b_ld[g][nt]];

#pragma unroll
        for (int g = 0; g < 3; ++g)
#pragma unroll
            for (int mt = 0; mt < 4; ++mt)
#pragma unroll
            for (int nt = 0; nt < 2; ++nt)
                acc[g][mt][nt] = __builtin_amdgcn_mfma_f32_16x16x32_bf16(
                    af[mt], bfr[g][nt], acc[g][mt][nt], 0, 0, 0);
    }

    const int colbase = n0 + wave_n * 32 + (lane & 15);
    float bi[2], bc[2], bo[2];
#pragma unroll
    for (int nt = 0; nt < 2; ++nt) {
        const int col = colbase + nt * 16;
        if (isbf) {
            bi[nt] = bf2f(((const u16*)bxi)[col]);
            bc[nt] = bf2f(((const u16*)bxc)[col]);
            bo[nt] = bf2f(((const u16*)bxo)[col]);
        } else {
            bi[nt] = ((const float*)bxi)[col];
            bc[nt] = ((const float*)bxc)[col];
            bo[nt] = ((const float*)bxo)[col];
        }
    }

    const int rowbase = m0 + wave_m * 64 + (lane >> 4) * 4;
#pragma unroll
    for (int mt = 0; mt < 4; ++mt)
#pragma unroll
        for (int nt = 0; nt < 2; ++nt)
#pragma unroll
            for (int r = 0; r < 4; ++r) {
                const int row = rowbase + mt * 16 + r;
                const int col = colbase + nt * 16;
                const float iv = fast_sigmoid(acc[0][mt][nt][r] + bi[nt]);
                const float cv = iv * fast_tanh(acc[1][mt][nt][r] + bc[nt]);
                const float ov = fast_sigmoid(acc[2][mt][nt][r] + bo[nt]);
                const float hv = ov * fast_tanh(cv);
                const long idx = (long)row * 512 + col;
                if (isbf) {
                    ((u16*)out)[idx]            = f2bf16u(hv);
                    ((u16*)out)[BH_ELEMS + idx] = f2bf16u(cv);
                } else {
                    ((float*)out)[idx]            = hv;
                    ((float*)out)[BH_ELEMS + idx] = cv;
                }
            }
}

extern "C" void kernel_launch(void* const* d_in, const int* in_sizes, int n_in,
                              void* d_out, int out_size, void* d_ws, size_t ws_size,
                              hipStream_t stream) {
    const void* x   = d_in[0];
    const void* h   = d_in[1];
    // d_in[2] = c_prev: dead in reference math, not read.
    const void* Wxi = d_in[3];
    const void* bxi = d_in[4];
    const void* Whi = d_in[5];
    // d_in[6..8] = Wxf/bxf/Whf: f gate is computed-then-discarded -> skipped.
    const void* Wxc = d_in[9];
    const void* bxc = d_in[10];
    const void* Whc = d_in[11];
    const void* Wxo = d_in[12];
    const void* bxo = d_in[13];
    const void* Who = d_in[14];

    u16* Wt = (u16*)d_ws;                         // 3 MB packed weights (bf16)

    prep<<<dim3(1536), dim3(256), 0, stream>>>(
        x, Wxi, Whi, Wxc, Whc, Wxo, Who, Wt);

    if (ws_size >= WT_BYTES) {
        lstm_gemm_v4<<<dim3(2048), dim3(256), 0, stream>>>(
            x, h, Wt, bxi, bxc, bxo, d_out);
    } else {
        lstm_gemm_fb<<<dim3(8, 256), dim3(256), 0, stream>>>(
            x, h, Wt, bxi, bxc, bxo, d_out);
    }
}